// Round 7
// baseline (1139.804 us; speedup 1.0000x reference)
//
#include <hip/hip_runtime.h>
#include <hip/hip_bf16.h>
#include <cstdint>

#define DEVFN __device__ __forceinline__

namespace {

constexpr int B = 16, T = 8192, C = 128, H = 128, K = 5;
constexpr int TP1 = T + 1;                      // 8193 slots (slot 0 = init row)
constexpr int NKK = 20;                         // (C*K)/32 K-steps
constexpr int NCH = T / 64;                     // 128 chunks over slots [1+64j, 64+64j]
constexpr int NSER = B * H;                     // 2048 scan series
constexpr int WF_ELE = NKK * 8 * 64 * 2 * 8;    // bf16 fragment elems (F+Z interleaved)
constexpr int XPITCH = 136;                     // LDS row pitch in shorts (272 B = 17*16B)

typedef __attribute__((ext_vector_type(8))) short short8;
typedef __attribute__((ext_vector_type(4))) float f32x4;

DEVFN float sigmoidf(float x) { return 1.0f / (1.0f + __expf(-x)); }
DEVFN unsigned bfb(float v) {
  __hip_bfloat16 h = __float2bfloat16(v);
  return (unsigned)*reinterpret_cast<unsigned short*>(&h);
}

// Segment-summary compose: L=[..b] then R=[b+1..]:
//   P* = P*_L * Fl_L * P*_R ; Q = Fl_L * P*_R * Q_L + Q_R ; Fl = Fl_R
// State transition through a segment S from (y,F): y' = F*S.P*y + S.Q ; F' = S.Fl
DEVFN void compose(float& P, float& Q, float& Fl, float Pr, float Qr, float Flr) {
  float t = Fl * Pr;
  P = P * t;
  Q = fmaf(t, Q, Qr);
  Fl = Flr;
}

// ---------------------------------------------------------------------------
// Weights (H,C,K) f32 -> MFMA B-fragment layout bf16 (16x16x32), F/Z interleaved:
//   idx = (((kk*8 + nf8)*64 + lane)*2 + fz)*8 + j
//   value = Bmat[kdim = kk*32 + (lane>>4)*8 + j][h = nf8*16 + (lane&15)]
//   fz==0 -> f_w, fz==1 -> z_w.
__global__ __launch_bounds__(256)
void wprep_kernel(const float* __restrict__ fw, const float* __restrict__ zw,
                  short* __restrict__ Wfrag) {
  int idx = blockIdx.x * 256 + threadIdx.x;
  if (idx >= WF_ELE) return;
  int j = idx & 7;
  int fz = (idx >> 3) & 1;
  int lane = (idx >> 4) & 63;
  int nf8 = (idx >> 10) & 7;
  int kk = idx >> 13;
  int kdim = kk * 32 + ((lane >> 4) << 3) + j;
  int h = nf8 * 16 + (lane & 15);
  int k = kdim >> 7, c = kdim & 127;
  int src = (h * C + c) * K + k;
  float w = fz ? zw[src] : fw[src];
  Wfrag[idx] = (short)bfb(w);
}

// ---------------------------------------------------------------------------
// Fused conv + single-pass scan (decoupled lookback, rocPRIM pattern).
// Block (chunk j, batch b), 8 waves. Conv core identical to round-6 best.
// Epilogue: F,G kept in acc regs; per-chunk (P,Q,Fl) aggregate published
// with agent-scope flags; waves 0-1 look back over predecessors; in-register
// Kogge-Stone prefix rescan writes `out` directly. FG/scanB/scanC deleted
// (saves 135 MB HBM round-trip + 2 launches).
__global__ __launch_bounds__(512, 4)
void conv_scan_kernel(const float* __restrict__ x,
                      const float* __restrict__ fb, const float* __restrict__ zb,
                      const float* __restrict__ initst,
                      const short* __restrict__ Wfrag,
                      float4* __restrict__ agg,      // per (b,chunk,h): P,Q,Fl,_
                      float2* __restrict__ pref,     // per (b,chunk,h): y_end, F_end
                      unsigned* __restrict__ flags,  // per (b,chunk): 0/1(agg)/2(prefix)
                      float* __restrict__ out) {
  __shared__ short xs[68 * XPITCH];  // rows r <-> t = t0-2+r; 272B pitch
  __shared__ float2 ybc[H];          // (y_in, F_in) per h, lookback -> rescan
  const int b = blockIdx.y;
  const int cblk = blockIdx.x;
  const int t0 = cblk * 64;
  const int tid = threadIdx.x;
  const int lane = tid & 63;
  const int wid = tid >> 6;          // 0..7 = h-col group
  const int lrow = lane & 15;
  const int lg = lane >> 4;

  // ---- stage x tile as bf16 (68 rows x 128 c), linear padded layout ----
  for (int i = tid; i < 68 * 16; i += 512) {
    int r = i >> 4, co = (i & 15) << 3;
    int t = t0 - 2 + r;
    f32x4 v0 = {0.f, 0.f, 0.f, 0.f}, v1 = v0;
    if (t >= 0 && t < T) {
      const f32x4* p = reinterpret_cast<const f32x4*>(x + ((size_t)(b * T + t)) * C + co);
      v0 = p[0]; v1 = p[1];
    }
    short8 s;
    s[0] = (short)bfb(v0[0]); s[1] = (short)bfb(v0[1]); s[2] = (short)bfb(v0[2]); s[3] = (short)bfb(v0[3]);
    s[4] = (short)bfb(v1[0]); s[5] = (short)bfb(v1[1]); s[6] = (short)bfb(v1[2]); s[7] = (short)bfb(v1[3]);
    *reinterpret_cast<short8*>(xs + r * XPITCH + co) = s;
  }
  __syncthreads();

  f32x4 accF[4], accZ[4];
#pragma unroll
  for (int mf = 0; mf < 4; ++mf) { accF[mf] = {0.f,0.f,0.f,0.f}; accZ[mf] = {0.f,0.f,0.f,0.f}; }

  const char* xsb = reinterpret_cast<const char*>(xs);
  const short8* wb = reinterpret_cast<const short8*>(Wfrag) + (wid * 128 + lane * 2);
  const int abase = lrow * 272 + lg * 16;

  // ---- software-pipelined K-loop (round-6 schedule, unchanged) ----
  short8 wf[4], wz[4], av[2][4];
#pragma unroll
  for (int p = 0; p < 3; ++p) {
    wf[p] = wb[p * 1024];
    wz[p] = wb[p * 1024 + 1];
  }
#pragma unroll
  for (int mf = 0; mf < 4; ++mf)
    av[0][mf] = *reinterpret_cast<const short8*>(xsb + (abase + (mf * 16) * 272));

#pragma unroll
  for (int kk = 0; kk < NKK; ++kk) {
    __builtin_amdgcn_sched_barrier(0);
    if (kk + 3 < NKK) {
      const int o = (kk + 3) * 1024;
      wf[(kk + 3) & 3] = wb[o];
      wz[(kk + 3) & 3] = wb[o + 1];
    }
    if (kk + 1 < NKK) {
      const int k1 = (kk + 1) >> 2;
      const int cq1 = ((kk + 1) & 3) << 6;
#pragma unroll
      for (int mf = 0; mf < 4; ++mf)
        av[(kk + 1) & 1][mf] =
            *reinterpret_cast<const short8*>(xsb + (abase + (mf * 16 + k1) * 272 + cq1));
    }
    __builtin_amdgcn_sched_barrier(0);
#pragma unroll
    for (int mf = 0; mf < 4; ++mf) {
      accF[mf] = __builtin_amdgcn_mfma_f32_16x16x32_bf16(av[kk & 1][mf], wf[kk & 3], accF[mf], 0, 0, 0);
      accZ[mf] = __builtin_amdgcn_mfma_f32_16x16x32_bf16(av[kk & 1][mf], wz[kk & 3], accZ[mf], 0, 0, 0);
    }
  }

  // ---- pass A: F,G in regs; per-(mf,lg) segment summaries; chunk aggregate ----
  const int h = wid * 16 + lrow;
  const float biasF = fb[h], biasZ = zb[h];
  float segP[4], segQ[4], segFl[4];
  float cP = 1.f, cQ = 0.f, cFl = 1.f;
#pragma unroll
  for (int mf = 0; mf < 4; ++mf) {
    float y = 0.f, P = 1.f, prevF = 1.f;
#pragma unroll
    for (int j = 0; j < 4; ++j) {
      float F = sigmoidf(accF[mf][j] + biasF);
      float G = sigmoidf(accZ[mf][j] + biasZ) * (1.0f - F);
      accF[mf][j] = F;                         // keep for rescan
      accZ[mf][j] = G;
      if (j == 0) { y = G; P = 1.f; }
      else { P *= prevF; y = fmaf(prevF, y, G); }
      prevF = F;
    }
    segP[mf] = P; segQ[mf] = y; segFl[mf] = prevF;
    // compose across lg (tree valid on lg==0) for the chunk aggregate
    float tP = P, tQ = y, tFl = prevF;
    {
      float pP = __shfl(tP, lane + 16, 64);
      float pQ = __shfl(tQ, lane + 16, 64);
      float pF = __shfl(tFl, lane + 16, 64);
      compose(tP, tQ, tFl, pP, pQ, pF);
      pP = __shfl(tP, lane + 32, 64);
      pQ = __shfl(tQ, lane + 32, 64);
      pF = __shfl(tFl, lane + 32, 64);
      compose(tP, tQ, tFl, pP, pQ, pF);
    }
    if (mf == 0) { cP = tP; cQ = tQ; cFl = tFl; }
    else compose(cP, cQ, cFl, tP, tQ, tFl);
  }
  const int sb = b * NCH;                      // series base for flags/agg/pref
  if (lg == 0) agg[(size_t)(sb + cblk) * H + h] = make_float4(cP, cQ, cFl, 0.f);
  __threadfence();
  __syncthreads();
  if (tid == 0)
    __hip_atomic_store(&flags[sb + cblk], 1u, __ATOMIC_RELEASE, __HIP_MEMORY_SCOPE_AGENT);

  // ---- decoupled lookback (waves 0,1; lane -> h = wid*64+lane) ----
  if (wid < 2) {
    const int hh = wid * 64 + lane;
    float4 myagg = agg[(size_t)(sb + cblk) * H + hh];
    float yin = 0.f, Fin = 0.f;
    float sP = 1.f, sQ = 0.f, sFl = 1.f;
    bool sValid = false;
    int i = cblk - 1;
    for (;;) {
      if (i < 0) {
        float F0 = sigmoidf(initst[b * H + hh]);
        float z0 = sigmoidf(initst[NSER + b * H + hh]);
        float y0 = z0 * (1.0f - F0);
        if (cblk == 0) out[(size_t)b * TP1 * H + hh] = y0;   // slot 0
        if (!sValid) { yin = y0; Fin = F0; }
        else { yin = fmaf(F0 * sP, y0, sQ); Fin = sFl; }
        break;
      }
      unsigned f = __hip_atomic_load(&flags[sb + i], __ATOMIC_ACQUIRE, __HIP_MEMORY_SCOPE_AGENT);
      if (f == 0u) { __builtin_amdgcn_s_sleep(2); continue; }
      if (f == 2u) {
        float2 pf = pref[(size_t)(sb + i) * H + hh];
        if (!sValid) { yin = pf.x; Fin = pf.y; }
        else { yin = fmaf(pf.y * sP, pf.x, sQ); Fin = sFl; }
        break;
      }
      // aggregate only: prepend S_i to suffix (S = S_i o Ssuf)
      float4 ai = agg[(size_t)(sb + i) * H + hh];
      if (!sValid) { sP = ai.x; sQ = ai.y; sFl = ai.z; sValid = true; }
      else {
        float t = ai.z * sP;          // Fl_L * P_R
        sQ = fmaf(t, ai.y, sQ);
        sP = ai.x * t;
      }
      --i;
    }
    // publish inclusive prefix (state after this chunk)
    float yend = fmaf(Fin * myagg.x, yin, myagg.y);
    pref[(size_t)(sb + cblk) * H + hh] = make_float2(yend, myagg.z);
    ybc[hh] = make_float2(yin, Fin);
    __threadfence();
  }
  __syncthreads();
  if (tid == 0)
    __hip_atomic_store(&flags[sb + cblk], 2u, __ATOMIC_RELEASE, __HIP_MEMORY_SCOPE_AGENT);

  // ---- in-register prefix rescan + out stores ----
  float2 yF = ybc[h];
  float ycur = yF.x, Fcur = yF.y;              // state entering this chunk
#pragma unroll
  for (int mf = 0; mf < 4; ++mf) {
    // Kogge-Stone inclusive scan of the 4 lg-segments (order lg=0..3)
    float iP = segP[mf], iQ = segQ[mf], iFl = segFl[mf];
    {
      float pP = __shfl_up(iP, 16, 64), pQ = __shfl_up(iQ, 16, 64), pF = __shfl_up(iFl, 16, 64);
      if (lg >= 1) { float t = pF * iP; iQ = fmaf(t, pQ, iQ); iP = pP * t; }
      pP = __shfl_up(iP, 32, 64); pQ = __shfl_up(iQ, 32, 64); pF = __shfl_up(iFl, 32, 64);
      if (lg >= 2) { float t = pF * iP; iQ = fmaf(t, pQ, iQ); iP = pP * t; }
    }
    // exclusive = inclusive shifted down one lg (valid lg>=1)
    float eP = __shfl_up(iP, 16, 64), eQ = __shfl_up(iQ, 16, 64), eFl = __shfl_up(iFl, 16, 64);
    // mf total = inclusive at lg==3, broadcast
    float mP = __shfl(iP, lrow + 48, 64), mQ = __shfl(iQ, lrow + 48, 64), mFl = __shfl(iFl, lrow + 48, 64);
    // segment-entry state
    float ys, Fs;
    if (lg == 0) { ys = ycur; Fs = Fcur; }
    else { ys = fmaf(Fcur * eP, ycur, eQ); Fs = eFl; }
    // 4 rows: y[s] = F[s-1]*y[s-1] + G[s]
#pragma unroll
    for (int j = 0; j < 4; ++j) {
      int s = t0 + mf * 16 + lg * 4 + j + 1;
      ys = fmaf(Fs, ys, accZ[mf][j]);
      Fs = accF[mf][j];
      out[(size_t)(b * TP1 + s) * H + h] = ys;
    }
    // advance chunk state by mf total
    ycur = fmaf(Fcur * mP, ycur, mQ);
    Fcur = mFl;
  }
}

}  // namespace

// ---------------------------------------------------------------------------
extern "C" void kernel_launch(void* const* d_in, const int* in_sizes, int n_in,
                              void* d_out, int out_size, void* d_ws, size_t ws_size,
                              hipStream_t stream) {
  const float* x    = (const float*)d_in[0];
  const float* init = (const float*)d_in[1];
  const float* zw   = (const float*)d_in[2];
  const float* zb   = (const float*)d_in[3];
  const float* fw   = (const float*)d_in[4];
  const float* fb   = (const float*)d_in[5];
  float* out = (float*)d_out;
  char* ws = (char*)d_ws;

  // ws layout: agg float4[B*NCH*H] (4MB) | pref float2[B*NCH*H] (2MB) |
  //            flags u32[B*NCH] (8KB, padded to 64KB) | Wfrag (0.33MB)
  constexpr size_t AGG_BYTES  = (size_t)B * NCH * H * sizeof(float4);
  constexpr size_t PREF_BYTES = (size_t)B * NCH * H * sizeof(float2);
  constexpr size_t FLAG_BYTES = (size_t)B * NCH * sizeof(unsigned);
  float4* agg     = (float4*)ws;
  float2* pref    = (float2*)(ws + AGG_BYTES);
  unsigned* flags = (unsigned*)(ws + AGG_BYTES + PREF_BYTES);
  short* Wfrag    = (short*)(ws + AGG_BYTES + PREF_BYTES + 65536);

  hipMemsetAsync(flags, 0, FLAG_BYTES, stream);
  wprep_kernel<<<(WF_ELE + 255) / 256, 256, 0, stream>>>(fw, zw, Wfrag);
  conv_scan_kernel<<<dim3(NCH, B), 512, 0, stream>>>(x, fb, zb, init, Wfrag,
                                                     agg, pref, flags, out);
}

// Round 8
// 100.078 us; speedup vs baseline: 11.3892x; 11.3892x over previous
//
#include <hip/hip_runtime.h>
#include <hip/hip_bf16.h>
#include <hip/hip_cooperative_groups.h>
#include <cstdint>

#define DEVFN __device__ __forceinline__

namespace {

constexpr int B = 16, T = 8192, C = 128, H = 128, K = 5;
constexpr int TP1 = T + 1;                      // 8193 slots (slot 0 = init row)
constexpr int N = B * TP1 * H;                  // 16,779,264
constexpr int NKK = 20;                         // (C*K)/32 K-steps
constexpr int NCH = T / 64;                     // 128 chunks over slots [1+64j, 64+64j]
constexpr int NSER = B * H;                     // 2048 scan series
constexpr int WF_ELE = NKK * 8 * 64 * 2 * 8;    // bf16 fragment elems (F+Z interleaved)
constexpr int XPITCH = 136;                     // LDS row pitch in shorts (272 B = 17*16B)
constexpr int XHALF = 68 * XPITCH;              // one staging buffer (shorts)

typedef __attribute__((ext_vector_type(8))) short short8;
typedef __attribute__((ext_vector_type(4))) float f32x4;

DEVFN float sigmoidf(float x) { return 1.0f / (1.0f + __expf(-x)); }
DEVFN unsigned bfb(float v) {
  __hip_bfloat16 h = __float2bfloat16(v);
  return (unsigned)*reinterpret_cast<unsigned short*>(&h);
}

// Segment-summary compose: L=[..b] then R=[b+1..]:
//   P* = P*_L * Fl_L * P*_R ; Q = Fl_L * P*_R * Q_L + Q_R ; Fl = Fl_R
DEVFN void compose(float& P, float& Q, float& Fl, float Pr, float Qr, float Flr) {
  float t = Fl * Pr;
  P = P * t;
  Q = fmaf(t, Q, Qr);
  Fl = Flr;
}

// ---------------------------------------------------------------------------
// Weights (H,C,K) f32 -> MFMA B-fragment layout bf16 (16x16x32), F/Z interleaved.
__global__ __launch_bounds__(256)
void wprep_kernel(const float* __restrict__ fw, const float* __restrict__ zw,
                  short* __restrict__ Wfrag) {
  int idx = blockIdx.x * 256 + threadIdx.x;
  if (idx >= WF_ELE) return;
  int j = idx & 7;
  int fz = (idx >> 3) & 1;
  int lane = (idx >> 4) & 63;
  int nf8 = (idx >> 10) & 7;
  int kk = idx >> 13;
  int kdim = kk * 32 + ((lane >> 4) << 3) + j;
  int h = nf8 * 16 + (lane & 15);
  int k = kdim >> 7, c = kdim & 127;
  int src = (h * C + c) * K + k;
  float w = fz ? zw[src] : fw[src];
  Wfrag[idx] = (short)bfb(w);
}

// ---- staging helpers (issue-early / write-late, T14) ----
DEVFN void stage_issue(const float* __restrict__ xp, int b, int t0, int tid,
                       f32x4& a0, f32x4& b0, f32x4& a1, f32x4& b1,
                       f32x4& a2, f32x4& b2) {
  auto ld = [&](int i, f32x4& va, f32x4& vb) {
    int r = i >> 4, co = (i & 15) << 3;
    int t = t0 - 2 + r;
    va = {0.f, 0.f, 0.f, 0.f}; vb = va;
    if (t >= 0 && t < T) {
      const f32x4* p = reinterpret_cast<const f32x4*>(xp + ((size_t)(b * T + t)) * C + co);
      va = p[0]; vb = p[1];
    }
  };
  ld(tid, a0, b0);
  ld(tid + 512, a1, b1);
  if (tid < 64) ld(tid + 1024, a2, b2);
}
DEVFN void stage_write(short* xsbuf, int tid,
                       f32x4& a0, f32x4& b0, f32x4& a1, f32x4& b1,
                       f32x4& a2, f32x4& b2) {
  auto st = [&](int i, f32x4& va, f32x4& vb) {
    int r = i >> 4, co = (i & 15) << 3;
    short8 s;
    s[0] = (short)bfb(va[0]); s[1] = (short)bfb(va[1]); s[2] = (short)bfb(va[2]); s[3] = (short)bfb(va[3]);
    s[4] = (short)bfb(vb[0]); s[5] = (short)bfb(vb[1]); s[6] = (short)bfb(vb[2]); s[7] = (short)bfb(vb[3]);
    *reinterpret_cast<short8*>(xsbuf + r * XPITCH + co) = s;
  };
  st(tid, a0, b0);
  st(tid + 512, a1, b1);
  if (tid < 64) st(tid + 1024, a2, b2);
}

// ---------------------------------------------------------------------------
// Fused cooperative kernel: 512 blocks x 512 thr, 2 blocks/CU co-resident.
// Block bid: batch b = bid>>5, chunk-quad q = bid&31 -> chunks 4q..4q+3.
// Phase A: conv per chunk (r6 core), xs double-buffered, stage issued early.
// Phase B (grid.sync): blocks 0-3 serial-scan chunk aggregates -> carry-ins.
// Phase C (grid.sync): rescan own 4 chunks (FG from local L2), write out.
__global__ __launch_bounds__(512, 4)
void fused_kernel(const float* __restrict__ x,
                  const float* __restrict__ fb, const float* __restrict__ zb,
                  const float* __restrict__ initst,
                  const short* __restrict__ Wfrag,
                  float2* __restrict__ stat,     // A: (P,Q); B rewrites: (y_in, F_in)
                  unsigned* __restrict__ FG,
                  float* __restrict__ out) {
  __shared__ short xs[2 * XHALF];
  const int bid = blockIdx.x;
  const int b = bid >> 5;
  const int q = bid & 31;
  const int tid = threadIdx.x;
  const int lane = tid & 63;
  const int wid = tid >> 6;
  const int lrow = lane & 15;
  const int lg = lane >> 4;

  const short8* wb = reinterpret_cast<const short8*>(Wfrag) + (wid * 128 + lane * 2);
  const int abase = lrow * 272 + lg * 16;
  const int h = wid * 16 + lrow;
  const float biasF = fb[h], biasZ = zb[h];

  f32x4 p0a, p0b, p1a, p1b, p2a, p2b;

  // ---- initial stage (chunk 4q) into buffer 0 ----
  stage_issue(x, b, q * 256, tid, p0a, p0b, p1a, p1b, p2a, p2b);
  stage_write(xs, tid, p0a, p0b, p1a, p1b, p2a, p2b);
  __syncthreads();

#pragma unroll 1
  for (int c = 0; c < 4; ++c) {
    const int t0 = (q * 4 + c) * 64;
    const char* xsb = reinterpret_cast<const char*>(xs + (c & 1) * XHALF);

    f32x4 accF[4], accZ[4];
#pragma unroll
    for (int mf = 0; mf < 4; ++mf) { accF[mf] = {0.f,0.f,0.f,0.f}; accZ[mf] = {0.f,0.f,0.f,0.f}; }

    // ---- software-pipelined K-loop (round-6 schedule) ----
    short8 wf[4], wz[4], av[2][4];
#pragma unroll
    for (int p = 0; p < 3; ++p) {
      wf[p] = wb[p * 1024];
      wz[p] = wb[p * 1024 + 1];
    }
#pragma unroll
    for (int mf = 0; mf < 4; ++mf)
      av[0][mf] = *reinterpret_cast<const short8*>(xsb + (abase + (mf * 16) * 272));

#pragma unroll
    for (int kk = 0; kk < NKK; ++kk) {
      __builtin_amdgcn_sched_barrier(0);
      if (kk + 3 < NKK) {
        const int o = (kk + 3) * 1024;
        wf[(kk + 3) & 3] = wb[o];
        wz[(kk + 3) & 3] = wb[o + 1];
      }
      if (kk + 1 < NKK) {
        const int k1 = (kk + 1) >> 2;
        const int cq1 = ((kk + 1) & 3) << 6;
#pragma unroll
        for (int mf = 0; mf < 4; ++mf)
          av[(kk + 1) & 1][mf] =
              *reinterpret_cast<const short8*>(xsb + (abase + (mf * 16 + k1) * 272 + cq1));
      }
      __builtin_amdgcn_sched_barrier(0);
#pragma unroll
      for (int mf = 0; mf < 4; ++mf) {
        accF[mf] = __builtin_amdgcn_mfma_f32_16x16x32_bf16(av[kk & 1][mf], wf[kk & 3], accF[mf], 0, 0, 0);
        accZ[mf] = __builtin_amdgcn_mfma_f32_16x16x32_bf16(av[kk & 1][mf], wz[kk & 3], accZ[mf], 0, 0, 0);
      }
    }

    // ---- issue next chunk's staging loads (hide under epilogue) ----
    if (c < 3)
      stage_issue(x, b, t0 + 64, tid, p0a, p0b, p1a, p1b, p2a, p2b);
    __builtin_amdgcn_sched_barrier(0);

    // ---- epilogue: FG stores + chunk aggregate ----
    float cP = 1.f, cQ = 0.f, cFl = 1.f;
#pragma unroll
    for (int mf = 0; mf < 4; ++mf) {
      float y = 0.f, P = 1.f, prevF = 1.f;
#pragma unroll
      for (int j = 0; j < 4; ++j) {
        int m = mf * 16 + lg * 4 + j;
        int s = t0 + m + 1;
        float F = sigmoidf(accF[mf][j] + biasF);
        float G = sigmoidf(accZ[mf][j] + biasZ) * (1.0f - F);
        FG[(size_t)(b * TP1 + s) * H + h] = bfb(F) | (bfb(G) << 16);
        if (j == 0) { y = G; P = 1.f; }
        else { P *= prevF; y = fmaf(prevF, y, G); }
        prevF = F;
      }
      float tP = P, tQ = y, tFl = prevF;
      {
        float pP = __shfl(tP, lane + 16, 64);
        float pQ = __shfl(tQ, lane + 16, 64);
        float pF = __shfl(tFl, lane + 16, 64);
        compose(tP, tQ, tFl, pP, pQ, pF);
        pP = __shfl(tP, lane + 32, 64);
        pQ = __shfl(tQ, lane + 32, 64);
        pF = __shfl(tFl, lane + 32, 64);
        compose(tP, tQ, tFl, pP, pQ, pF);
      }
      if (mf == 0) { cP = tP; cQ = tQ; cFl = tFl; }
      else compose(cP, cQ, cFl, tP, tQ, tFl);
    }
    if (lg == 0)
      stat[(size_t)(b * NCH + q * 4 + c) * H + h] = make_float2(cP, cQ);

    // ---- write next chunk's stage into the other buffer ----
    if (c < 3) {
      __syncthreads();
      stage_write(xs + ((c + 1) & 1) * XHALF, tid, p0a, p0b, p1a, p1b, p2a, p2b);
      __syncthreads();
    }
  }

  cooperative_groups::this_grid().sync();

  // ---- phase B: serial chunk-level scan (blocks 0-3, one thread/series) ----
  if (bid < 4) {
    int g = bid * 512 + tid;                 // 0..2047 = b*128+h
    int b2 = g >> 7, h2 = g & (H - 1);
    float F0 = sigmoidf(initst[g]);
    float z0 = sigmoidf(initst[NSER + g]);
    float G0 = z0 * (1.0f - F0);
    size_t base = (size_t)b2 * TP1 * H + h2;
    out[base] = G0;                           // slot 0
    float y = G0, Fp = F0;
    for (int j = 0; j < NCH; ++j) {
      size_t sidx = (size_t)(b2 * NCH + j) * H + h2;
      float2 pq = stat[sidx];
      stat[sidx] = make_float2(y, Fp);        // carry-in for chunk j
      y = fmaf(Fp * pq.x, y, pq.y);
      if (j + 1 < NCH)
        Fp = __uint_as_float(FG[base + (size_t)(64 * (j + 1)) * H] << 16);
    }
  }

  cooperative_groups::this_grid().sync();

  // ---- phase C: rescan own 4 chunks (FG in local L2), write out ----
  {
    const int sub = tid >> 7;                 // 0..3 -> chunk q*4+sub
    const int h3 = tid & (H - 1);
    const int j = q * 4 + sub;
    float2 cf = stat[(size_t)(b * NCH + j) * H + h3];
    float y = cf.x, Fprev = cf.y;
    size_t base = (size_t)b * TP1 * H + h3;
    const unsigned* p = FG + base + (size_t)(1 + j * 64) * H;
    float* po = out + base + (size_t)(1 + j * 64) * H;
#pragma unroll 8
    for (int t = 0; t < 64; ++t) {
      unsigned u = *p; p += H;
      float G = __uint_as_float(u & 0xffff0000u);
      y = fmaf(Fprev, y, G);
      Fprev = __uint_as_float(u << 16);
      *po = y; po += H;
    }
  }
}

// ---------------------------------------------------------------------------
// -------- fallback path: round-6 three-kernel pipeline (verbatim) ----------
__global__ __launch_bounds__(512, 4)
void conv_mfma_kernel(const float* __restrict__ x,
                      const float* __restrict__ fb, const float* __restrict__ zb,
                      const short* __restrict__ Wfrag,
                      unsigned* __restrict__ FG,
                      float* __restrict__ sumP, float* __restrict__ sumQ) {
  __shared__ short xs[68 * XPITCH];
  const int b = blockIdx.y;
  const int t0 = blockIdx.x * 64;
  const int tid = threadIdx.x;
  const int lane = tid & 63;
  const int wid = tid >> 6;
  const int lrow = lane & 15;
  const int lg = lane >> 4;

  for (int i = tid; i < 68 * 16; i += 512) {
    int r = i >> 4, co = (i & 15) << 3;
    int t = t0 - 2 + r;
    f32x4 v0 = {0.f, 0.f, 0.f, 0.f}, v1 = v0;
    if (t >= 0 && t < T) {
      const f32x4* p = reinterpret_cast<const f32x4*>(x + ((size_t)(b * T + t)) * C + co);
      v0 = p[0]; v1 = p[1];
    }
    short8 s;
    s[0] = (short)bfb(v0[0]); s[1] = (short)bfb(v0[1]); s[2] = (short)bfb(v0[2]); s[3] = (short)bfb(v0[3]);
    s[4] = (short)bfb(v1[0]); s[5] = (short)bfb(v1[1]); s[6] = (short)bfb(v1[2]); s[7] = (short)bfb(v1[3]);
    *reinterpret_cast<short8*>(xs + r * XPITCH + co) = s;
  }
  __syncthreads();

  f32x4 accF[4], accZ[4];
#pragma unroll
  for (int mf = 0; mf < 4; ++mf) { accF[mf] = {0.f,0.f,0.f,0.f}; accZ[mf] = {0.f,0.f,0.f,0.f}; }

  const char* xsb = reinterpret_cast<const char*>(xs);
  const short8* wb = reinterpret_cast<const short8*>(Wfrag) + (wid * 128 + lane * 2);
  const int abase = lrow * 272 + lg * 16;

  short8 wf[4], wz[4], av[2][4];
#pragma unroll
  for (int p = 0; p < 3; ++p) {
    wf[p] = wb[p * 1024];
    wz[p] = wb[p * 1024 + 1];
  }
#pragma unroll
  for (int mf = 0; mf < 4; ++mf)
    av[0][mf] = *reinterpret_cast<const short8*>(xsb + (abase + (mf * 16) * 272));

#pragma unroll
  for (int kk = 0; kk < NKK; ++kk) {
    __builtin_amdgcn_sched_barrier(0);
    if (kk + 3 < NKK) {
      const int o = (kk + 3) * 1024;
      wf[(kk + 3) & 3] = wb[o];
      wz[(kk + 3) & 3] = wb[o + 1];
    }
    if (kk + 1 < NKK) {
      const int k1 = (kk + 1) >> 2;
      const int cq1 = ((kk + 1) & 3) << 6;
#pragma unroll
      for (int mf = 0; mf < 4; ++mf)
        av[(kk + 1) & 1][mf] =
            *reinterpret_cast<const short8*>(xsb + (abase + (mf * 16 + k1) * 272 + cq1));
    }
    __builtin_amdgcn_sched_barrier(0);
#pragma unroll
    for (int mf = 0; mf < 4; ++mf) {
      accF[mf] = __builtin_amdgcn_mfma_f32_16x16x32_bf16(av[kk & 1][mf], wf[kk & 3], accF[mf], 0, 0, 0);
      accZ[mf] = __builtin_amdgcn_mfma_f32_16x16x32_bf16(av[kk & 1][mf], wz[kk & 3], accZ[mf], 0, 0, 0);
    }
  }

  const int cblk = blockIdx.x;
  const int h = wid * 16 + lrow;
  const float biasF = fb[h], biasZ = zb[h];
  float cP = 1.f, cQ = 0.f, cFl = 1.f;
#pragma unroll
  for (int mf = 0; mf < 4; ++mf) {
    float y = 0.f, P = 1.f, prevF = 1.f;
#pragma unroll
    for (int j = 0; j < 4; ++j) {
      int m = mf * 16 + lg * 4 + j;
      int s = t0 + m + 1;
      float rf = accF[mf][j] + biasF;
      float rz = accZ[mf][j] + biasZ;
      float F = sigmoidf(rf);
      float G = sigmoidf(rz) * (1.0f - F);
      FG[(size_t)(b * TP1 + s) * H + h] = bfb(F) | (bfb(G) << 16);
      if (j == 0) { y = G; P = 1.f; }
      else { P *= prevF; y = fmaf(prevF, y, G); }
      prevF = F;
    }
    float tP = P, tQ = y, tFl = prevF;
    {
      float pP = __shfl(tP, lane + 16, 64);
      float pQ = __shfl(tQ, lane + 16, 64);
      float pF = __shfl(tFl, lane + 16, 64);
      compose(tP, tQ, tFl, pP, pQ, pF);
      pP = __shfl(tP, lane + 32, 64);
      pQ = __shfl(tQ, lane + 32, 64);
      pF = __shfl(tFl, lane + 32, 64);
      compose(tP, tQ, tFl, pP, pQ, pF);
    }
    if (mf == 0) { cP = tP; cQ = tQ; cFl = tFl; }
    else compose(cP, cQ, cFl, tP, tQ, tFl);
  }
  if (lg == 0) {
    int sidx = cblk * NSER + b * H + h;
    sumP[sidx] = cP;
    sumQ[sidx] = cQ;
  }
}

__global__ void scanB_kernel(const float* __restrict__ init,
                             const unsigned* __restrict__ FG_r,
                             unsigned* __restrict__ FG_w,
                             const float* __restrict__ sumQ,
                             float* __restrict__ sumP_cin,
                             float* __restrict__ out) {
  int g = blockIdx.x * blockDim.x + threadIdx.x;
  int b = g >> 7, h = g & (H - 1);
  float rf = init[g];
  float rz = init[NSER + g];
  float F0 = sigmoidf(rf), z = sigmoidf(rz);
  float G0 = z * (1.0f - F0);
  size_t base = (size_t)b * TP1 * H + h;
  FG_w[base] = bfb(F0) | (bfb(G0) << 16);
  out[base] = G0;
  float y = G0;
  float prevFl = F0;
  for (int j = 0; j < NCH; ++j) {
    int sidx = j * NSER + g;
    float Ps = sumP_cin[sidx];
    float Q  = sumQ[sidx];
    sumP_cin[sidx] = y;
    y = fmaf(prevFl * Ps, y, Q);
    if (j + 1 < NCH)
      prevFl = __uint_as_float(FG_r[base + (size_t)(64 * (j + 1)) * H] << 16);
  }
}

__global__ __launch_bounds__(128)
void scanC_kernel(const unsigned* __restrict__ FG, const float* __restrict__ cin,
                  float* __restrict__ out) {
  const int b = blockIdx.y, j = blockIdx.x, h = threadIdx.x;
  const int s0 = 1 + j * 64;
  float y = cin[j * NSER + b * H + h];
  const size_t base = (size_t)b * TP1 * H + h;
  const unsigned* p = FG + base + (size_t)s0 * H;
  float Fprev = __uint_as_float(p[-H] << 16);
  float* po = out + base + (size_t)s0 * H;
#pragma unroll 8
  for (int t = 0; t < 64; ++t) {
    unsigned u = *p; p += H;
    float G = __uint_as_float(u & 0xffff0000u);
    y = fmaf(Fprev, y, G);
    Fprev = __uint_as_float(u << 16);
    *po = y; po += H;
  }
}

}  // namespace

// ---------------------------------------------------------------------------
extern "C" void kernel_launch(void* const* d_in, const int* in_sizes, int n_in,
                              void* d_out, int out_size, void* d_ws, size_t ws_size,
                              hipStream_t stream) {
  const float* x    = (const float*)d_in[0];
  const float* init = (const float*)d_in[1];
  const float* zw   = (const float*)d_in[2];
  const float* zb   = (const float*)d_in[3];
  const float* fw   = (const float*)d_in[4];
  const float* fb   = (const float*)d_in[5];
  float* out = (float*)d_out;
  char* ws = (char*)d_ws;

  // ws layout: [0,4N) FG | stat float2[B*NCH*H] (2MB; fallback: sumP|sumQ) | Wfrag
  unsigned* FG  = (unsigned*)ws;
  float2*  stat = (float2*)(ws + (size_t)N * 4);
  float*   sumP = (float*)stat;
  float*   sumQ = sumP + (size_t)NCH * NSER;
  short*  Wfrag = (short*)(ws + (size_t)N * 4 + (size_t)NCH * NSER * 8);

  wprep_kernel<<<(WF_ELE + 255) / 256, 256, 0, stream>>>(fw, zw, Wfrag);

  bool coop = false;
  int nb = 0;
  if (hipOccupancyMaxActiveBlocksPerMultiprocessor(
          &nb, (const void*)fused_kernel, 512, 0) == hipSuccess && nb >= 2) {
    void* args[] = {(void*)&x, (void*)&fb, (void*)&zb, (void*)&init,
                    (void*)&Wfrag, (void*)&stat, (void*)&FG, (void*)&out};
    coop = hipLaunchCooperativeKernel((const void*)fused_kernel, dim3(512), dim3(512),
                                      args, 0, stream) == hipSuccess;
  }
  if (!coop) {
    conv_mfma_kernel<<<dim3(NCH, B), 512, 0, stream>>>(x, fb, zb, Wfrag, FG, sumP, sumQ);
    scanB_kernel<<<16, 128, 0, stream>>>(init, FG, FG, sumQ, sumP, out);
    scanC_kernel<<<dim3(NCH, B), 128, 0, stream>>>(FG, sumP, out);
  }
}